// Round 7
// baseline (83.987 us; speedup 1.0000x reference)
//
#include <hip/hip_runtime.h>
#include <math.h>

#define N_TOK 2048
#define D_MODEL 512
#define NHEAD 8
#define DK 64
#define LOG2E 1.44269504f
#define QSCALE 0.18033688f   // 0.125 * log2(e)

typedef __attribute__((ext_vector_type(8))) short short8;
typedef __attribute__((ext_vector_type(4))) short short4v;
typedef __attribute__((ext_vector_type(4))) float f32x4;

__device__ __forceinline__ short f2bf(float x) {
    unsigned u = __float_as_uint(x);
    u = (u + 0x7fffu + ((u >> 16) & 1u)) >> 16;   // round-to-nearest-even
    return (short)u;
}

__device__ __forceinline__ unsigned cvt_pk_bf16(float lo, float hi) {
    unsigned r;
    asm("v_cvt_pk_bf16_f32 %0, %1, %2" : "=v"(r) : "v"(lo), "v"(hi));
    return r;
}

__device__ __forceinline__ float head_c(int h) {
    // c_h = -log2e / (2*spread^2), spread = 1 + 5*(20^(h/7)-1)/19
    float tt = (float)h * (1.0f / 7.0f);
    float sp = 1.0f + 5.0f * (__builtin_exp2f(tt * 4.3219281f) - 1.0f) * (1.0f / 19.0f);
    return -LOG2E / (2.0f * sp * sp);
}

// ---------------- Prep A: x (q,k,v) f32 -> bf16 ----------------
__global__ __launch_bounds__(256) void convert_x_kernel(
    const float* __restrict__ q, const float* __restrict__ k,
    const float* __restrict__ v, short* __restrict__ Xbf)
{
    int i = blockIdx.x * 256 + threadIdx.x;
    int t = i >> 17;
    int rem = i & 131071;
    const float4* src = (const float4*)(t == 0 ? q : (t == 1 ? k : v));
    float4 a = src[rem * 2], b = src[rem * 2 + 1];
    short8 o;
    o[0] = f2bf(a.x); o[1] = f2bf(a.y); o[2] = f2bf(a.z); o[3] = f2bf(a.w);
    o[4] = f2bf(b.x); o[5] = f2bf(b.y); o[6] = f2bf(b.z); o[7] = f2bf(b.w);
    *(short8*)(Xbf + (size_t)i * 8) = o;
}

// ---------------- Prep B: weights -> bf16 (proj transposed) ----------------
__global__ __launch_bounds__(256) void prep_w_kernel(
    const float* __restrict__ qp, const float* __restrict__ kp,
    const float* __restrict__ vp, const float* __restrict__ ow,
    short* __restrict__ Wt, short* __restrict__ Wo)
{
    const int z = blockIdx.z, t = threadIdx.x;
    if (z == 3) {
        int m0 = blockIdx.x * 64, j0 = blockIdx.y * 64;
        for (int i = t; i < 4096; i += 256) {
            int r = i >> 6, c = i & 63;
            size_t idx = (size_t)(m0 + r) * 512 + j0 + c;
            Wo[idx] = f2bf(ow[idx]);
        }
        return;
    }
    const float* src = z == 0 ? qp : (z == 1 ? kp : vp);
    __shared__ float tile[64][65];
    const int h = blockIdx.x;
    const int d0 = blockIdx.y * 64;
    for (int i = t; i < 4096; i += 256) {
        int r = i >> 6, c = i & 63;
        tile[r][c] = src[((size_t)h * 512 + d0 + r) * 64 + c];
    }
    __syncthreads();
    short* W = Wt + (size_t)z * 512 * 512;
    for (int i = t; i < 4096; i += 256) {
        int cr = i >> 6, dc_ = i & 63;
        W[(size_t)(h * 64 + cr) * 512 + d0 + dc_] = f2bf(tile[dc_][cr]);
    }
}

// ---------------- Prep C: RBF tables ----------------
// ck4[h][j] = {-2c_h*kx, -2c_h*ky, -2c_h*kz, c_h*|k|^2}; mpen[j]; tflag[j/64]
__global__ __launch_bounds__(256) void prep_rbf_kernel(
    const float* __restrict__ coords, const unsigned char* __restrict__ mask,
    float4* __restrict__ ck4, float* __restrict__ mpen, unsigned* __restrict__ tflag)
{
    int j = blockIdx.x * 256 + threadIdx.x;
    float x = coords[j * 3 + 0], y = coords[j * 3 + 1], z = coords[j * 3 + 2];
    unsigned char mk = mask[j];
    mpen[j] = mk ? -1e9f : 0.f;
    unsigned long long b = __ballot(mk != 0);
    if ((threadIdx.x & 63) == 0) tflag[j >> 6] = (b != 0ull) ? 1u : 0u;
    float n2 = x * x + y * y + z * z;
    #pragma unroll
    for (int h = 0; h < NHEAD; ++h) {
        float c = head_c(h);
        float4 o; o.x = -2.f * c * x; o.y = -2.f * c * y; o.z = -2.f * c * z; o.w = c * n2;
        ck4[(size_t)h * N_TOK + j] = o;
    }
}

// ---------------- Stage 1: projection + LayerNorm via bf16 MFMA ------------
// z=0: Q row-major [h][n][dk], pre-scaled by 0.125*log2e.
// z=1: K in MFMA-fragment tile order. z=2: V in fragment tile order (B=V^T A-op).
__global__ __launch_bounds__(256) void proj_ln_mfma_kernel(
    const short* __restrict__ Xbf, const short* __restrict__ Wt,
    const float* __restrict__ qlw, const float* __restrict__ qlb,
    const float* __restrict__ klw, const float* __restrict__ klb,
    const float* __restrict__ vlw, const float* __restrict__ vlb,
    short* __restrict__ Qbf, short* __restrict__ Kf, short* __restrict__ Vf)
{
    __shared__ short Xs[64 * 64];
    __shared__ short Ws[64 * 64];
    const int z = blockIdx.z, h = blockIdx.y;
    const int n0 = blockIdx.x * 64;
    const int tid = threadIdx.x, w = tid >> 6, l = tid & 63;
    const int l15 = l & 15, lg = l >> 4;

    const short* X = Xbf + (size_t)z * N_TOK * D_MODEL;
    const short* Wz = Wt + ((size_t)z * 512 + h * 64) * 512;

    const f32x4 zero4 = {0.f, 0.f, 0.f, 0.f};
    f32x4 acc[4];
    #pragma unroll
    for (int dc = 0; dc < 4; ++dc) acc[dc] = zero4;

    for (int kb = 0; kb < 8; ++kb) {
        const int d0 = kb * 64;
        __syncthreads();
        #pragma unroll
        for (int i = 0; i < 2; ++i) {
            int c = tid + i * 256;
            int r = c >> 3, g = c & 7;
            short8 xv = *(const short8*)(X + (size_t)(n0 + r) * 512 + d0 + g * 8);
            *(short8*)(Xs + r * 64 + ((g * 8) ^ ((r & 7) << 3))) = xv;
            short8 wv = *(const short8*)(Wz + (size_t)r * 512 + d0 + g * 8);
            *(short8*)(Ws + r * 64 + ((g * 8) ^ ((r & 7) << 3))) = wv;
        }
        __syncthreads();
        const int arow = w * 16 + l15;
        short8 a0 = *(const short8*)(Xs + arow * 64 + ((lg * 8) ^ ((arow & 7) << 3)));
        short8 a1 = *(const short8*)(Xs + arow * 64 + ((32 + lg * 8) ^ ((arow & 7) << 3)));
        #pragma unroll
        for (int dc = 0; dc < 4; ++dc) {
            const int brow = dc * 16 + l15;
            short8 b0 = *(const short8*)(Ws + brow * 64 + ((lg * 8) ^ ((brow & 7) << 3)));
            acc[dc] = __builtin_amdgcn_mfma_f32_16x16x32_bf16(a0, b0, acc[dc], 0, 0, 0);
            short8 b1 = *(const short8*)(Ws + brow * 64 + ((32 + lg * 8) ^ ((brow & 7) << 3)));
            acc[dc] = __builtin_amdgcn_mfma_f32_16x16x32_bf16(a1, b1, acc[dc], 0, 0, 0);
        }
    }

    const float* lw  = z == 0 ? qlw : (z == 1 ? klw : vlw);
    const float* lbp = z == 0 ? qlb : (z == 1 ? klb : vlb);
    float wv_[4], bv_[4];
    #pragma unroll
    for (int dc = 0; dc < 4; ++dc) {
        wv_[dc] = lw[dc * 16 + l15];
        bv_[dc] = lbp[dc * 16 + l15];
    }
    float mu[4], rs[4];
    #pragma unroll
    for (int reg = 0; reg < 4; ++reg) {
        float s = acc[0][reg] + acc[1][reg] + acc[2][reg] + acc[3][reg];
        #pragma unroll
        for (int off = 1; off < 16; off <<= 1) s += __shfl_xor(s, off);
        float m = s * (1.0f / 64.0f);
        float ss = 0.f;
        #pragma unroll
        for (int dc = 0; dc < 4; ++dc) { float d = acc[dc][reg] - m; ss += d * d; }
        #pragma unroll
        for (int off = 1; off < 16; off <<= 1) ss += __shfl_xor(ss, off);
        mu[reg] = m;
        rs[reg] = rsqrtf(ss * (1.0f / 64.0f) + 1e-5f);
    }

    const int tile = n0 >> 6;
    if (z == 0) {
        #pragma unroll
        for (int dc = 0; dc < 4; ++dc)
            #pragma unroll
            for (int reg = 0; reg < 4; ++reg) {
                int n = n0 + w * 16 + lg * 4 + reg;
                float val = ((acc[dc][reg] - mu[reg]) * rs[reg] * wv_[dc] + bv_[dc]) * QSCALE;
                Qbf[((size_t)h * N_TOK + n) * DK + dc * 16 + l15] = f2bf(val);
            }
    } else if (z == 1) {
        // fragment order: Kf[h] + tile*4096 + (nc*2+hf)*512 + (l15c+16*lgc)*8 + e
        short* Kh = Kf + (size_t)h * N_TOK * DK;
        #pragma unroll
        for (int dc = 0; dc < 4; ++dc) {
            int hf  = dc >> 1;
            int lgc = ((dc & 1) << 1) | (l15 >> 3);
            int e   = l15 & 7;
            size_t base = (size_t)tile * 4096 + (w * 2 + hf) * 512 + 16 * 8 * lgc + e;
            #pragma unroll
            for (int reg = 0; reg < 4; ++reg) {
                float val = (acc[dc][reg] - mu[reg]) * rs[reg] * wv_[dc] + bv_[dc];
                Kh[base + (lg * 4 + reg) * 8] = f2bf(val);
            }
        }
    } else {
        // fragment order: Vf[h] + tile*4096 + (dcc*2+hf)*512 + (l15+16*lgv)*8 + e
        short* Vh = Vf + (size_t)h * N_TOK * DK;
        int hfv = w >> 1;
        int lgv = ((w & 1) << 1) | (lg >> 1);
        int eb  = (lg & 1) * 4;
        #pragma unroll
        for (int dc = 0; dc < 4; ++dc) {
            short4v p;
            #pragma unroll
            for (int reg = 0; reg < 4; ++reg)
                p[reg] = f2bf((acc[dc][reg] - mu[reg]) * rs[reg] * wv_[dc] + bv_[dc]);
            size_t addr = (size_t)tile * 4096 + (dc * 2 + hfv) * 512 + (l15 + 16 * lgv) * 8 + eb;
            *(short4v*)(Vh + addr) = p;
        }
    }
}

// ---------------- Stage 2: swapped flash attention (bf16 MFMA) -------------
// grid (N/16, H), block 256 = 4 waves. 16 shared q-rows; wave w owns keys
// [w*512,(w+1)*512) in 8 steps of 64, fully unrolled with a 2-deep K
// register pipeline (K(t+1) prefetched during softmax/PV of step t) and
// V(t) loads issued at step top (covered by QK+softmax). Swapped mfma(K,Q):
// lane owns ONE q-row -> scalar softmax state, 2 shfls per step.
__global__ __launch_bounds__(256) void attn_kernel(
    const short* __restrict__ Qbf, const short* __restrict__ Kf,
    const short* __restrict__ Vf, const float* __restrict__ coords,
    const float4* __restrict__ ck4, const float* __restrict__ mpen,
    const unsigned* __restrict__ tflag, short* __restrict__ att)
{
    __shared__ short Pls[4][1024];       // per-wave P [16 q][64 k], swizzled
    __shared__ float bufO[2][64][17];
    __shared__ float bufM[2][64];
    __shared__ float bufL[2][64];

    const int tid = threadIdx.x;
    const int w = tid >> 6, l = tid & 63;
    const int l15 = l & 15, lg = l >> 4;
    const int h = blockIdx.y;
    const int n0 = blockIdx.x * 16;

    char* Pb = (char*)&Pls[w][0];
    const int psw = (l15 & 7) << 4;      // byte-xor swizzle within 128B row

    // Q B-fragments (row q = n0+l15, d-halves)
    const short* Qrow = Qbf + ((size_t)h * N_TOK + n0 + l15) * DK + lg * 8;
    const short8 qf0 = *(const short8*)(Qrow);
    const short8 qf1 = *(const short8*)(Qrow + 32);

    const float ch = head_c(h);
    const float qx = coords[(n0 + l15) * 3 + 0];
    const float qy = coords[(n0 + l15) * 3 + 1];
    const float qz = coords[(n0 + l15) * 3 + 2];
    const float cq2 = ch * (qx * qx + qy * qy + qz * qz);
    const float4* ckh = ck4 + (size_t)h * N_TOK;

    const f32x4 zero4 = {0.f, 0.f, 0.f, 0.f};
    float m_ = -INFINITY, l_ = 0.f;
    f32x4 oacc[4];
    #pragma unroll
    for (int i = 0; i < 4; ++i) oacc[i] = zero4;

    const short* Kfh = Kf + (size_t)h * N_TOK * DK;
    const short* Vfh = Vf + (size_t)h * N_TOK * DK;

    short8 ka[4][2], kb[4][2];
    {   // prologue: K fragments for step 0
        const short* kp_ = Kfh + (size_t)(w * 8) * 4096 + l * 8;
        #pragma unroll
        for (int nc = 0; nc < 4; ++nc) {
            ka[nc][0] = *(const short8*)(kp_ + nc * 1024);
            ka[nc][1] = *(const short8*)(kp_ + nc * 1024 + 512);
        }
    }

#define ATTN_STEP(KCUR, KNXT, T, PREF) do {                                    \
    const int kt_ = w * 8 + (T);                                               \
    const int kbase_ = kt_ * 64;                                               \
    /* V(t) loads issued first: consumed at PV, covered by QK+softmax */       \
    const short* vp_ = Vfh + (size_t)kt_ * 4096 + l * 8;                       \
    short8 vb_[4][2];                                                          \
    _Pragma("unroll")                                                          \
    for (int dcc = 0; dcc < 4; ++dcc) {                                        \
        vb_[dcc][0] = *(const short8*)(vp_ + dcc * 1024);                      \
        vb_[dcc][1] = *(const short8*)(vp_ + dcc * 1024 + 512);                \
    }                                                                          \
    f32x4 sacc[4];                                                             \
    __builtin_amdgcn_s_setprio(1);                                             \
    _Pragma("unroll")                                                          \
    for (int nc = 0; nc < 4; ++nc) {                                           \
        sacc[nc] = __builtin_amdgcn_mfma_f32_16x16x32_bf16(KCUR[nc][0], qf0, zero4, 0, 0, 0); \
        sacc[nc] = __builtin_amdgcn_mfma_f32_16x16x32_bf16(KCUR[nc][1], qf1, sacc[nc], 0, 0, 0); \
    }                                                                          \
    __builtin_amdgcn_s_setprio(0);                                             \
    if (PREF) { /* K(t+1) prefetch: covered by softmax + PV */                 \
        const short* kp_ = Kfh + (size_t)(kt_ + 1) * 4096 + l * 8;             \
        _Pragma("unroll")                                                      \
        for (int nc = 0; nc < 4; ++nc) {                                       \
            KNXT[nc][0] = *(const short8*)(kp_ + nc * 1024);                   \
            KNXT[nc][1] = *(const short8*)(kp_ + nc * 1024 + 512);             \
        }                                                                      \
    }                                                                          \
    /* RBF modulation (log2 domain; Q pre-scaled by 0.125*log2e) */            \
    _Pragma("unroll")                                                          \
    for (int nc = 0; nc < 4; ++nc) {                                           \
        _Pragma("unroll")                                                      \
        for (int reg = 0; reg < 4; ++reg) {                                    \
            float4 c4 = ckh[kbase_ + nc * 16 + lg * 4 + reg];                  \
            float arg = fmaf(c4.x, qx, fmaf(c4.y, qy, fmaf(c4.z, qz, c4.w))) + cq2; \
            float rb = __builtin_exp2f(arg);                                   \
            rb = fminf(fmaxf(rb, 0.1f), 0.9f);                                 \
            sacc[nc][reg] *= rb;                                               \
        }                                                                      \
    }                                                                          \
    if (tflag[kt_]) {                                                          \
        _Pragma("unroll")                                                      \
        for (int nc = 0; nc < 4; ++nc)                                         \
            _Pragma("unroll")                                                  \
            for (int reg = 0; reg < 4; ++reg)                                  \
                sacc[nc][reg] += mpen[kbase_ + nc * 16 + lg * 4 + reg];        \
    }                                                                          \
    /* row max: in-register tree + 2 shfls */                                  \
    float mx = -INFINITY;                                                      \
    _Pragma("unroll")                                                          \
    for (int nc = 0; nc < 4; ++nc) {                                           \
        float a_ = fmaxf(sacc[nc][0], sacc[nc][1]);                            \
        float b_ = fmaxf(sacc[nc][2], sacc[nc][3]);                            \
        mx = fmaxf(mx, fmaxf(a_, b_));                                         \
    }                                                                          \
    mx = fmaxf(mx, __shfl_xor(mx, 16));                                        \
    mx = fmaxf(mx, __shfl_xor(mx, 32));                                        \
    /* defer-max rescale (skip when growth bounded: P <= 2^8) */               \
    if (!__all(mx <= m_ + 8.0f)) {                                             \
        float mn = fmaxf(m_, mx);                                              \
        float corr = __builtin_exp2f(m_ - mn);                                 \
        m_ = mn;                                                               \
        l_ *= corr;                                                            \
        _Pragma("unroll")                                                      \
        for (int dc = 0; dc < 4; ++dc) oacc[dc] *= corr;                       \
    }                                                                          \
    /* P = exp2(s-m), sum, pack -> LDS */                                      \
    float ps = 0.f;                                                            \
    _Pragma("unroll")                                                          \
    for (int nc = 0; nc < 4; ++nc) {                                           \
        float p0 = __builtin_exp2f(sacc[nc][0] - m_);                          \
        float p1 = __builtin_exp2f(sacc[nc][1] - m_);                          \
        float p2 = __builtin_exp2f(sacc[nc][2] - m_);                          \
        float p3 = __builtin_exp2f(sacc[nc][3] - m_);                          \
        ps += (p0 + p1) + (p2 + p3);                                           \
        uint2 u;                                                               \
        u.x = cvt_pk_bf16(p0, p1);                                             \
        u.y = cvt_pk_bf16(p2, p3);                                             \
        *(uint2*)(Pb + ((l15 * 128 + nc * 32 + lg * 8) ^ psw)) = u;            \
    }                                                                          \
    ps += __shfl_xor(ps, 16);                                                  \
    ps += __shfl_xor(ps, 32);                                                  \
    l_ += ps;                                                                  \
    /* PV (swapped): O^T += V^T * P^T */                                       \
    short8 pf0 = *(const short8*)(Pb + ((l15 * 128 + lg * 16) ^ psw));         \
    short8 pf1 = *(const short8*)(Pb + ((l15 * 128 + 64 + lg * 16) ^ psw));    \
    __builtin_amdgcn_s_setprio(1);                                             \
    _Pragma("unroll")                                                          \
    for (int dcc = 0; dcc < 4; ++dcc) {                                        \
        oacc[dcc] = __builtin_amdgcn_mfma_f32_16x16x32_bf16(vb_[dcc][0], pf0, oacc[dcc], 0, 0, 0); \
        oacc[dcc] = __builtin_amdgcn_mfma_f32_16x16x32_bf16(vb_[dcc][1], pf1, oacc[dcc], 0, 0, 0); \
    }                                                                          \
    __builtin_amdgcn_s_setprio(0);                                             \
} while (0)

    ATTN_STEP(ka, kb, 0, 1);
    ATTN_STEP(kb, ka, 1, 1);
    ATTN_STEP(ka, kb, 2, 1);
    ATTN_STEP(kb, ka, 3, 1);
    ATTN_STEP(ka, kb, 4, 1);
    ATTN_STEP(kb, ka, 5, 1);
    ATTN_STEP(ka, kb, 6, 1);
    ATTN_STEP(kb, ka, 7, 0);
#undef ATTN_STEP

    // ---- cross-wave tree merge (lane-aligned: same (q,d) mapping per wave) --
    if (w >= 2) {
        int slot = w - 2;
        bufM[slot][l] = m_; bufL[slot][l] = l_;
        #pragma unroll
        for (int dc = 0; dc < 4; ++dc)
            #pragma unroll
            for (int reg = 0; reg < 4; ++reg)
                bufO[slot][l][dc * 4 + reg] = oacc[dc][reg];
    }
    __syncthreads();
    if (w < 2) {
        float mb = bufM[w][l], lb = bufL[w][l];
        float M = fmaxf(m_, mb);
        float fa = __builtin_exp2f(m_ - M), fb = __builtin_exp2f(mb - M);
        l_ = l_ * fa + lb * fb; m_ = M;
        #pragma unroll
        for (int dc = 0; dc < 4; ++dc)
            #pragma unroll
            for (int reg = 0; reg < 4; ++reg)
                oacc[dc][reg] = oacc[dc][reg] * fa + bufO[w][l][dc * 4 + reg] * fb;
    }
    __syncthreads();
    if (w == 1) {
        bufM[0][l] = m_; bufL[0][l] = l_;
        #pragma unroll
        for (int dc = 0; dc < 4; ++dc)
            #pragma unroll
            for (int reg = 0; reg < 4; ++reg)
                bufO[0][l][dc * 4 + reg] = oacc[dc][reg];
    }
    __syncthreads();
    if (w == 0) {
        float mb = bufM[0][l], lb = bufL[0][l];
        float M = fmaxf(m_, mb);
        float fa = __builtin_exp2f(m_ - M), fb = __builtin_exp2f(mb - M);
        l_ = l_ * fa + lb * fb;
        float rl = 1.0f / l_;
        #pragma unroll
        for (int dcc = 0; dcc < 4; ++dcc)
            #pragma unroll
            for (int reg = 0; reg < 4; ++reg) {
                float o = (oacc[dcc][reg] * fa + bufO[0][l][dcc * 4 + reg] * fb) * rl;
                att[(size_t)(n0 + l15) * D_MODEL + (dcc * 16 + lg * 4 + reg) * NHEAD + h] = f2bf(o);
            }
    }
}

// ---------------- Stage 3: output projection via bf16 MFMA ----------------
__global__ __launch_bounds__(256) void out_proj_kernel(
    const short* __restrict__ ATT, const short* __restrict__ Wo,
    const float* __restrict__ bias, float* __restrict__ out)
{
    __shared__ short As[64 * 64];
    __shared__ short Bs[64 * 64];
    const int n0 = blockIdx.x * 64, m0 = blockIdx.y * 64;
    const int tid = threadIdx.x, w = tid >> 6, l = tid & 63;
    const int l15 = l & 15, lg = l >> 4;

    const f32x4 zero4 = {0.f, 0.f, 0.f, 0.f};
    f32x4 acc[4];
    #pragma unroll
    for (int dc = 0; dc < 4; ++dc) acc[dc] = zero4;

    for (int kb = 0; kb < 8; ++kb) {
        const int j0 = kb * 64;
        __syncthreads();
        #pragma unroll
        for (int i = 0; i < 2; ++i) {
            int c = tid + i * 256;
            int r = c >> 3, g = c & 7;
            short8 av = *(const short8*)(ATT + (size_t)(n0 + r) * 512 + j0 + g * 8);
            *(short8*)(As + r * 64 + ((g * 8) ^ ((r & 7) << 3))) = av;
            short8 bv = *(const short8*)(Wo + (size_t)(m0 + r) * 512 + j0 + g * 8);
            *(short8*)(Bs + r * 64 + ((g * 8) ^ ((r & 7) << 3))) = bv;
        }
        __syncthreads();
        const int arow = w * 16 + l15;
        short8 a0 = *(const short8*)(As + arow * 64 + ((lg * 8) ^ ((arow & 7) << 3)));
        short8 a1 = *(const short8*)(As + arow * 64 + ((32 + lg * 8) ^ ((arow & 7) << 3)));
        #pragma unroll
        for (int dc = 0; dc < 4; ++dc) {
            const int brow = dc * 16 + l15;
            short8 b0 = *(const short8*)(Bs + brow * 64 + ((lg * 8) ^ ((brow & 7) << 3)));
            acc[dc] = __builtin_amdgcn_mfma_f32_16x16x32_bf16(a0, b0, acc[dc], 0, 0, 0);
            short8 b1 = *(const short8*)(Bs + brow * 64 + ((32 + lg * 8) ^ ((brow & 7) << 3)));
            acc[dc] = __builtin_amdgcn_mfma_f32_16x16x32_bf16(a1, b1, acc[dc], 0, 0, 0);
        }
    }

    #pragma unroll
    for (int dc = 0; dc < 4; ++dc) {
        float bm = bias[m0 + dc * 16 + l15];
        #pragma unroll
        for (int reg = 0; reg < 4; ++reg) {
            int n = n0 + w * 16 + lg * 4 + reg;
            out[(size_t)n * D_MODEL + m0 + dc * 16 + l15] = acc[dc][reg] + bm;
        }
    }
}

extern "C" void kernel_launch(void* const* d_in, const int* in_sizes, int n_in,
                              void* d_out, int out_size, void* d_ws, size_t ws_size,
                              hipStream_t stream)
{
    const float* q      = (const float*)d_in[0];
    const float* k      = (const float*)d_in[1];
    const float* v      = (const float*)d_in[2];
    const float* coords = (const float*)d_in[3];
    const unsigned char* mask = (const unsigned char*)d_in[4];
    const float* q_proj = (const float*)d_in[5];
    const float* k_proj = (const float*)d_in[6];
    const float* v_proj = (const float*)d_in[7];
    const float* q_ln_w = (const float*)d_in[8];
    const float* q_ln_b = (const float*)d_in[9];
    const float* k_ln_w = (const float*)d_in[10];
    const float* k_ln_b = (const float*)d_in[11];
    const float* v_ln_w = (const float*)d_in[12];
    const float* v_ln_b = (const float*)d_in[13];
    const float* out_w  = (const float*)d_in[14];
    const float* out_b  = (const float*)d_in[15];
    float* out = (float*)d_out;

    // workspace layout
    short* Xbf = (short*)d_ws;             // 3*2048*512
    short* Wt  = Xbf + 3145728;            // 3*512*512
    short* Wo  = Wt + 786432;              // 512*512
    short* Qbf = Wo + 262144;              // 8*2048*64
    short* Kf  = Qbf + 1048576;            // fragment-ordered
    short* Vf  = Kf + 1048576;             // fragment-ordered
    short* ATT = Vf + 1048576;             // [n][dk*8+h] bf16
    float*  fr   = (float*)(ATT + 1048576);
    float4* ck4  = (float4*)fr;            // 8*2048 float4
    float*  mpen = fr + 65536;             // 2048
    unsigned* tflag = (unsigned*)(mpen + 2048);  // 32

    convert_x_kernel<<<dim3(1536), dim3(256), 0, stream>>>(q, k, v, Xbf);
    prep_w_kernel<<<dim3(8, 8, 4), dim3(256), 0, stream>>>(q_proj, k_proj, v_proj, out_w, Wt, Wo);
    prep_rbf_kernel<<<dim3(8), dim3(256), 0, stream>>>(coords, mask, ck4, mpen, tflag);
    proj_ln_mfma_kernel<<<dim3(32, 8, 3), dim3(256), 0, stream>>>(
        Xbf, Wt, q_ln_w, q_ln_b, k_ln_w, k_ln_b, v_ln_w, v_ln_b, Qbf, Kf, Vf);
    attn_kernel<<<dim3(128, 8), dim3(256), 0, stream>>>(Qbf, Kf, Vf, coords, ck4, mpen, tflag, ATT);
    out_proj_kernel<<<dim3(32, 8), dim3(256), 0, stream>>>(ATT, Wo, out_b, out);
}

// Round 8
// 78.966 us; speedup vs baseline: 1.0636x; 1.0636x over previous
//
#include <hip/hip_runtime.h>
#include <math.h>

#define N_TOK 2048
#define D_MODEL 512
#define NHEAD 8
#define DK 64
#define LOG2E 1.44269504f
#define QSCALE 0.18033688f   // 0.125 * log2(e)

typedef __attribute__((ext_vector_type(8))) short short8;
typedef __attribute__((ext_vector_type(4))) short short4v;
typedef __attribute__((ext_vector_type(4))) float f32x4;

__device__ __forceinline__ short f2bf(float x) {
    unsigned u = __float_as_uint(x);
    u = (u + 0x7fffu + ((u >> 16) & 1u)) >> 16;   // round-to-nearest-even
    return (short)u;
}

__device__ __forceinline__ float bf2f(short s) {
    return __uint_as_float(((unsigned)(unsigned short)s) << 16);
}

__device__ __forceinline__ unsigned cvt_pk_bf16(float lo, float hi) {
    unsigned r;
    asm("v_cvt_pk_bf16_f32 %0, %1, %2" : "=v"(r) : "v"(lo), "v"(hi));
    return r;
}

__device__ __forceinline__ float head_c(int h) {
    // c_h = -log2e / (2*spread^2), spread = 1 + 5*(20^(h/7)-1)/19
    float tt = (float)h * (1.0f / 7.0f);
    float sp = 1.0f + 5.0f * (__builtin_exp2f(tt * 4.3219281f) - 1.0f) * (1.0f / 19.0f);
    return -LOG2E / (2.0f * sp * sp);
}

// ---------------- Prep A: x (q,k,v) f32 -> bf16 ----------------
__global__ __launch_bounds__(256) void convert_x_kernel(
    const float* __restrict__ q, const float* __restrict__ k,
    const float* __restrict__ v, short* __restrict__ Xbf)
{
    int i = blockIdx.x * 256 + threadIdx.x;
    int t = i >> 17;
    int rem = i & 131071;
    const float4* src = (const float4*)(t == 0 ? q : (t == 1 ? k : v));
    float4 a = src[rem * 2], b = src[rem * 2 + 1];
    short8 o;
    o[0] = f2bf(a.x); o[1] = f2bf(a.y); o[2] = f2bf(a.z); o[3] = f2bf(a.w);
    o[4] = f2bf(b.x); o[5] = f2bf(b.y); o[6] = f2bf(b.z); o[7] = f2bf(b.w);
    *(short8*)(Xbf + (size_t)i * 8) = o;
}

// ---------------- Prep B: weights -> bf16 (proj transposed) ----------------
// z<3: Wt[z][h*64+c][d] = proj_z[h][d][c].
// z==3: Wo[m][h*64+k] = out_w[m][k*8+h]  (K-dim permuted to match ATT layout).
__global__ __launch_bounds__(256) void prep_w_kernel(
    const float* __restrict__ qp, const float* __restrict__ kp,
    const float* __restrict__ vp, const float* __restrict__ ow,
    short* __restrict__ Wt, short* __restrict__ Wo)
{
    const int z = blockIdx.z, t = threadIdx.x;
    if (z == 3) {
        int m0 = blockIdx.x * 64, j0 = blockIdx.y * 64;
        int hh = j0 >> 6;
        for (int i = t; i < 4096; i += 256) {
            int r = i >> 6, kk = i & 63;
            Wo[(size_t)(m0 + r) * 512 + j0 + kk] =
                f2bf(ow[(size_t)(m0 + r) * 512 + kk * 8 + hh]);
        }
        return;
    }
    const float* src = z == 0 ? qp : (z == 1 ? kp : vp);
    __shared__ float tile[64][65];
    const int h = blockIdx.x;
    const int d0 = blockIdx.y * 64;
    for (int i = t; i < 4096; i += 256) {
        int r = i >> 6, c = i & 63;
        tile[r][c] = src[((size_t)h * 512 + d0 + r) * 64 + c];
    }
    __syncthreads();
    short* W = Wt + (size_t)z * 512 * 512;
    for (int i = t; i < 4096; i += 256) {
        int cr = i >> 6, dc_ = i & 63;
        W[(size_t)(h * 64 + cr) * 512 + d0 + dc_] = f2bf(tile[dc_][cr]);
    }
}

// ---------------- Prep C: RBF tables ----------------
// ck4[h][j] = {-2c_h*kx, -2c_h*ky, -2c_h*kz, c_h*|k|^2}; mpen[j]; tflag[j/64]
__global__ __launch_bounds__(256) void prep_rbf_kernel(
    const float* __restrict__ coords, const unsigned char* __restrict__ mask,
    float4* __restrict__ ck4, float* __restrict__ mpen, unsigned* __restrict__ tflag)
{
    int j = blockIdx.x * 256 + threadIdx.x;
    float x = coords[j * 3 + 0], y = coords[j * 3 + 1], z = coords[j * 3 + 2];
    unsigned char mk = mask[j];
    mpen[j] = mk ? -1e9f : 0.f;
    unsigned long long b = __ballot(mk != 0);
    if ((threadIdx.x & 63) == 0) tflag[j >> 6] = (b != 0ull) ? 1u : 0u;
    float n2 = x * x + y * y + z * z;
    #pragma unroll
    for (int h = 0; h < NHEAD; ++h) {
        float c = head_c(h);
        float4 o; o.x = -2.f * c * x; o.y = -2.f * c * y; o.z = -2.f * c * z; o.w = c * n2;
        ck4[(size_t)h * N_TOK + j] = o;
    }
}

// ---------------- Stage 1: projection + LayerNorm via bf16 MFMA ------------
// z=0: Q row-major [h][n][dk], pre-scaled by 0.125*log2e.
// z=1: K in MFMA-fragment tile order. z=2: V in fragment tile order (B=V^T A-op).
__global__ __launch_bounds__(256) void proj_ln_mfma_kernel(
    const short* __restrict__ Xbf, const short* __restrict__ Wt,
    const float* __restrict__ qlw, const float* __restrict__ qlb,
    const float* __restrict__ klw, const float* __restrict__ klb,
    const float* __restrict__ vlw, const float* __restrict__ vlb,
    short* __restrict__ Qbf, short* __restrict__ Kf, short* __restrict__ Vf)
{
    __shared__ short Xs[64 * 64];
    __shared__ short Ws[64 * 64];
    const int z = blockIdx.z, h = blockIdx.y;
    const int n0 = blockIdx.x * 64;
    const int tid = threadIdx.x, w = tid >> 6, l = tid & 63;
    const int l15 = l & 15, lg = l >> 4;

    const short* X = Xbf + (size_t)z * N_TOK * D_MODEL;
    const short* Wz = Wt + ((size_t)z * 512 + h * 64) * 512;

    const f32x4 zero4 = {0.f, 0.f, 0.f, 0.f};
    f32x4 acc[4];
    #pragma unroll
    for (int dc = 0; dc < 4; ++dc) acc[dc] = zero4;

    for (int kb = 0; kb < 8; ++kb) {
        const int d0 = kb * 64;
        __syncthreads();
        #pragma unroll
        for (int i = 0; i < 2; ++i) {
            int c = tid + i * 256;
            int r = c >> 3, g = c & 7;
            short8 xv = *(const short8*)(X + (size_t)(n0 + r) * 512 + d0 + g * 8);
            *(short8*)(Xs + r * 64 + ((g * 8) ^ ((r & 7) << 3))) = xv;
            short8 wv = *(const short8*)(Wz + (size_t)r * 512 + d0 + g * 8);
            *(short8*)(Ws + r * 64 + ((g * 8) ^ ((r & 7) << 3))) = wv;
        }
        __syncthreads();
        const int arow = w * 16 + l15;
        short8 a0 = *(const short8*)(Xs + arow * 64 + ((lg * 8) ^ ((arow & 7) << 3)));
        short8 a1 = *(const short8*)(Xs + arow * 64 + ((32 + lg * 8) ^ ((arow & 7) << 3)));
        #pragma unroll
        for (int dc = 0; dc < 4; ++dc) {
            const int brow = dc * 16 + l15;
            short8 b0 = *(const short8*)(Ws + brow * 64 + ((lg * 8) ^ ((brow & 7) << 3)));
            acc[dc] = __builtin_amdgcn_mfma_f32_16x16x32_bf16(a0, b0, acc[dc], 0, 0, 0);
            short8 b1 = *(const short8*)(Ws + brow * 64 + ((32 + lg * 8) ^ ((brow & 7) << 3)));
            acc[dc] = __builtin_amdgcn_mfma_f32_16x16x32_bf16(a1, b1, acc[dc], 0, 0, 0);
        }
    }

    const float* lw  = z == 0 ? qlw : (z == 1 ? klw : vlw);
    const float* lbp = z == 0 ? qlb : (z == 1 ? klb : vlb);
    float wv_[4], bv_[4];
    #pragma unroll
    for (int dc = 0; dc < 4; ++dc) {
        wv_[dc] = lw[dc * 16 + l15];
        bv_[dc] = lbp[dc * 16 + l15];
    }
    float mu[4], rs[4];
    #pragma unroll
    for (int reg = 0; reg < 4; ++reg) {
        float s = acc[0][reg] + acc[1][reg] + acc[2][reg] + acc[3][reg];
        #pragma unroll
        for (int off = 1; off < 16; off <<= 1) s += __shfl_xor(s, off);
        float m = s * (1.0f / 64.0f);
        float ss = 0.f;
        #pragma unroll
        for (int dc = 0; dc < 4; ++dc) { float d = acc[dc][reg] - m; ss += d * d; }
        #pragma unroll
        for (int off = 1; off < 16; off <<= 1) ss += __shfl_xor(ss, off);
        mu[reg] = m;
        rs[reg] = rsqrtf(ss * (1.0f / 64.0f) + 1e-5f);
    }

    const int tile = n0 >> 6;
    if (z == 0) {
        #pragma unroll
        for (int dc = 0; dc < 4; ++dc)
            #pragma unroll
            for (int reg = 0; reg < 4; ++reg) {
                int n = n0 + w * 16 + lg * 4 + reg;
                float val = ((acc[dc][reg] - mu[reg]) * rs[reg] * wv_[dc] + bv_[dc]) * QSCALE;
                Qbf[((size_t)h * N_TOK + n) * DK + dc * 16 + l15] = f2bf(val);
            }
    } else if (z == 1) {
        // fragment order: Kf[h] + tile*4096 + (nc*2+hf)*512 + (l15c+16*lgc)*8 + e
        short* Kh = Kf + (size_t)h * N_TOK * DK;
        #pragma unroll
        for (int dc = 0; dc < 4; ++dc) {
            int hf  = dc >> 1;
            int lgc = ((dc & 1) << 1) | (l15 >> 3);
            int e   = l15 & 7;
            size_t base = (size_t)tile * 4096 + (w * 2 + hf) * 512 + 16 * 8 * lgc + e;
            #pragma unroll
            for (int reg = 0; reg < 4; ++reg) {
                float val = (acc[dc][reg] - mu[reg]) * rs[reg] * wv_[dc] + bv_[dc];
                Kh[base + (lg * 4 + reg) * 8] = f2bf(val);
            }
        }
    } else {
        // fragment order: Vf[h] + tile*4096 + (dcc*2+hf)*512 + (l15+16*lgv)*8 + e
        short* Vh = Vf + (size_t)h * N_TOK * DK;
        int hfv = w >> 1;
        int lgv = ((w & 1) << 1) | (lg >> 1);
        int eb  = (lg & 1) * 4;
        #pragma unroll
        for (int dc = 0; dc < 4; ++dc) {
            short4v p;
            #pragma unroll
            for (int reg = 0; reg < 4; ++reg)
                p[reg] = f2bf((acc[dc][reg] - mu[reg]) * rs[reg] * wv_[dc] + bv_[dc]);
            size_t addr = (size_t)tile * 4096 + (dc * 2 + hfv) * 512 + (l15 + 16 * lgv) * 8 + eb;
            *(short4v*)(Vh + addr) = p;
        }
    }
}

// ---------------- Stage 2: split-K flash attention (bf16 MFMA) -------------
// grid (N/16, H, 2), block 256 = 4 waves. Block z covers keys
// [z*1024,(z+1)*1024); wave w covers 256 keys in 4 steps of 64.
// Swapped mfma(K,Q): lane owns ONE q-row -> scalar softmax, 2 shfls/step.
// Block writes UNNORMALIZED partial (m, l, O bf16) -> merged by merge_kernel.
__global__ __launch_bounds__(256) void attn_kernel(
    const short* __restrict__ Qbf, const short* __restrict__ Kf,
    const short* __restrict__ Vf, const float* __restrict__ coords,
    const float4* __restrict__ ck4, const float* __restrict__ mpen,
    const unsigned* __restrict__ tflag,
    short* __restrict__ PO, float* __restrict__ PM, float* __restrict__ PL)
{
    __shared__ short Pls[4][1024];       // per-wave P [16 q][64 k], swizzled
    __shared__ float bufO[2][64][17];
    __shared__ float bufM[2][64];
    __shared__ float bufL[2][64];

    const int tid = threadIdx.x;
    const int w = tid >> 6, l = tid & 63;
    const int l15 = l & 15, lg = l >> 4;
    const int h = blockIdx.y;
    const int z = blockIdx.z;
    const int n0 = blockIdx.x * 16;

    char* Pb = (char*)&Pls[w][0];
    const int psw = (l15 & 7) << 4;      // byte-xor swizzle within 128B row

    // Q B-fragments (row q = n0+l15, d-halves)
    const short* Qrow = Qbf + ((size_t)h * N_TOK + n0 + l15) * DK + lg * 8;
    const short8 qf0 = *(const short8*)(Qrow);
    const short8 qf1 = *(const short8*)(Qrow + 32);

    const float ch = head_c(h);
    const float qx = coords[(n0 + l15) * 3 + 0];
    const float qy = coords[(n0 + l15) * 3 + 1];
    const float qz = coords[(n0 + l15) * 3 + 2];
    const float cq2 = ch * (qx * qx + qy * qy + qz * qz);
    const float4* ckh = ck4 + (size_t)h * N_TOK;

    const f32x4 zero4 = {0.f, 0.f, 0.f, 0.f};
    float m_ = -INFINITY, l_ = 0.f;
    f32x4 oacc[4];
    #pragma unroll
    for (int i = 0; i < 4; ++i) oacc[i] = zero4;

    const short* Kfh = Kf + (size_t)h * N_TOK * DK;
    const short* Vfh = Vf + (size_t)h * N_TOK * DK;

    for (int t = 0; t < 4; ++t) {
        const int kt = (z * 4 + w) * 4 + t;  // global 64-key tile
        const int kbase = kt * 64;
        const short* kp = Kfh + (size_t)kt * 4096 + l * 8;
        const short* vp = Vfh + (size_t)kt * 4096 + l * 8;

        // ---- QK^T (swapped): S^T[k][q], lane: q=l15, k = nc*16+lg*4+reg ----
        f32x4 sacc[4];
        #pragma unroll
        for (int nc = 0; nc < 4; ++nc) {
            short8 k0 = *(const short8*)(kp + nc * 1024);
            short8 k1 = *(const short8*)(kp + nc * 1024 + 512);
            sacc[nc] = __builtin_amdgcn_mfma_f32_16x16x32_bf16(k0, qf0, zero4, 0, 0, 0);
            sacc[nc] = __builtin_amdgcn_mfma_f32_16x16x32_bf16(k1, qf1, sacc[nc], 0, 0, 0);
        }

        // ---- RBF modulation (log2 domain; Q pre-scaled by 0.125*log2e) ----
        #pragma unroll
        for (int nc = 0; nc < 4; ++nc) {
            #pragma unroll
            for (int reg = 0; reg < 4; ++reg) {
                float4 c4 = ckh[kbase + nc * 16 + lg * 4 + reg];
                float arg = fmaf(c4.x, qx, fmaf(c4.y, qy, fmaf(c4.z, qz, c4.w))) + cq2;
                float rb = __builtin_exp2f(arg);
                rb = fminf(fmaxf(rb, 0.1f), 0.9f);
                sacc[nc][reg] *= rb;
            }
        }
        if (tflag[kt]) {
            #pragma unroll
            for (int nc = 0; nc < 4; ++nc)
                #pragma unroll
                for (int reg = 0; reg < 4; ++reg)
                    sacc[nc][reg] += mpen[kbase + nc * 16 + lg * 4 + reg];
        }

        // ---- row max: in-register tree + 2 shfls ----
        float mx = -INFINITY;
        #pragma unroll
        for (int nc = 0; nc < 4; ++nc) {
            float a = fmaxf(sacc[nc][0], sacc[nc][1]);
            float b = fmaxf(sacc[nc][2], sacc[nc][3]);
            mx = fmaxf(mx, fmaxf(a, b));
        }
        mx = fmaxf(mx, __shfl_xor(mx, 16));
        mx = fmaxf(mx, __shfl_xor(mx, 32));

        // ---- defer-max rescale (skip when growth bounded: P <= 2^8) ----
        if (!__all(mx <= m_ + 8.0f)) {
            float mn = fmaxf(m_, mx);
            float corr = __builtin_exp2f(m_ - mn);
            m_ = mn;
            l_ *= corr;
            #pragma unroll
            for (int dc = 0; dc < 4; ++dc) oacc[dc] *= corr;
        }

        // ---- P = exp2(s-m), sum, pack -> LDS (b64 per nc) ----
        float ps = 0.f;
        #pragma unroll
        for (int nc = 0; nc < 4; ++nc) {
            float p0 = __builtin_exp2f(sacc[nc][0] - m_);
            float p1 = __builtin_exp2f(sacc[nc][1] - m_);
            float p2 = __builtin_exp2f(sacc[nc][2] - m_);
            float p3 = __builtin_exp2f(sacc[nc][3] - m_);
            ps += (p0 + p1) + (p2 + p3);
            uint2 u;
            u.x = cvt_pk_bf16(p0, p1);
            u.y = cvt_pk_bf16(p2, p3);
            *(uint2*)(Pb + ((l15 * 128 + nc * 32 + lg * 8) ^ psw)) = u;
        }
        ps += __shfl_xor(ps, 16);
        ps += __shfl_xor(ps, 32);
        l_ += ps;

        // ---- PV (swapped): O^T += V^T * P^T; lane: q=l15, d=dcc*16+lg*4+reg
        short8 pf0 = *(const short8*)(Pb + ((l15 * 128 + lg * 16) ^ psw));
        short8 pf1 = *(const short8*)(Pb + ((l15 * 128 + 64 + lg * 16) ^ psw));
        #pragma unroll
        for (int dcc = 0; dcc < 4; ++dcc) {
            short8 v0 = *(const short8*)(vp + dcc * 1024);
            short8 v1 = *(const short8*)(vp + dcc * 1024 + 512);
            oacc[dcc] = __builtin_amdgcn_mfma_f32_16x16x32_bf16(v0, pf0, oacc[dcc], 0, 0, 0);
            oacc[dcc] = __builtin_amdgcn_mfma_f32_16x16x32_bf16(v1, pf1, oacc[dcc], 0, 0, 0);
        }
    }

    // ---- cross-wave tree merge (lane-aligned: same (q,d) mapping per wave) --
    if (w >= 2) {
        int slot = w - 2;
        bufM[slot][l] = m_; bufL[slot][l] = l_;
        #pragma unroll
        for (int dc = 0; dc < 4; ++dc)
            #pragma unroll
            for (int reg = 0; reg < 4; ++reg)
                bufO[slot][l][dc * 4 + reg] = oacc[dc][reg];
    }
    __syncthreads();
    if (w < 2) {
        float mb = bufM[w][l], lb = bufL[w][l];
        float M = fmaxf(m_, mb);
        float fa = __builtin_exp2f(m_ - M), fb = __builtin_exp2f(mb - M);
        l_ = l_ * fa + lb * fb; m_ = M;
        #pragma unroll
        for (int dc = 0; dc < 4; ++dc)
            #pragma unroll
            for (int reg = 0; reg < 4; ++reg)
                oacc[dc][reg] = oacc[dc][reg] * fa + bufO[w][l][dc * 4 + reg] * fb;
    }
    __syncthreads();
    if (w == 1) {
        bufM[0][l] = m_; bufL[0][l] = l_;
        #pragma unroll
        for (int dc = 0; dc < 4; ++dc)
            #pragma unroll
            for (int reg = 0; reg < 4; ++reg)
                bufO[0][l][dc * 4 + reg] = oacc[dc][reg];
    }
    __syncthreads();
    if (w == 0) {
        float mb = bufM[0][l], lb = bufL[0][l];
        float M = fmaxf(m_, mb);
        float fa = __builtin_exp2f(m_ - M), fb = __builtin_exp2f(mb - M);
        float lf = l_ * fa + lb * fb;
        size_t p = ((size_t)z * NHEAD + h) * N_TOK + n0 + l15;
        if (lg == 0) { PM[p] = M; PL[p] = lf; }
        #pragma unroll
        for (int dcc = 0; dcc < 4; ++dcc) {
            short4v o4;
            #pragma unroll
            for (int reg = 0; reg < 4; ++reg)
                o4[reg] = f2bf(oacc[dcc][reg] * fa + bufO[0][l][dcc * 4 + reg] * fb);
            *(short4v*)(PO + p * 64 + dcc * 16 + lg * 4) = o4;
        }
    }
}

// ---------------- Stage 2b: merge the 2 KV-split partials ------------------
// grid (N/4, H), block 256 = 4 waves; wave u owns q = bx*4+u, lane = d.
// ATT layout: [n][h*64+d] (Wo K-dim permuted to match).
__global__ __launch_bounds__(256) void merge_kernel(
    const short* __restrict__ PO, const float* __restrict__ PM,
    const float* __restrict__ PL, short* __restrict__ ATT)
{
    const int t = threadIdx.x;
    const int u = t >> 6, d = t & 63;
    const int q = blockIdx.x * 4 + u;
    const int h = blockIdx.y;
    const size_t p0 = (size_t)h * N_TOK + q;
    const size_t p1 = (size_t)(NHEAD + h) * N_TOK + q;
    float m0 = PM[p0], m1 = PM[p1];
    float l0 = PL[p0], l1 = PL[p1];
    float M = fmaxf(m0, m1);
    float f0 = __builtin_exp2f(m0 - M), f1 = __builtin_exp2f(m1 - M);
    float rl = 1.0f / (l0 * f0 + l1 * f1);
    float o0 = bf2f(PO[p0 * 64 + d]), o1 = bf2f(PO[p1 * 64 + d]);
    ATT[(size_t)q * D_MODEL + h * 64 + d] = f2bf((o0 * f0 + o1 * f1) * rl);
}

// ---------------- Stage 3: output projection via bf16 MFMA ----------------
__global__ __launch_bounds__(256) void out_proj_kernel(
    const short* __restrict__ ATT, const short* __restrict__ Wo,
    const float* __restrict__ bias, float* __restrict__ out)
{
    __shared__ short As[64 * 64];
    __shared__ short Bs[64 * 64];
    const int n0 = blockIdx.x * 64, m0 = blockIdx.y * 64;
    const int tid = threadIdx.x, w = tid >> 6, l = tid & 63;
    const int l15 = l & 15, lg = l >> 4;

    const f32x4 zero4 = {0.f, 0.f, 0.f, 0.f};
    f32x4 acc[4];
    #pragma unroll
    for (int dc = 0; dc < 4; ++dc) acc[dc] = zero4;

    for (int kb = 0; kb < 8; ++kb) {
        const int j0 = kb * 64;
        __syncthreads();
        #pragma unroll
        for (int i = 0; i < 2; ++i) {
            int c = tid + i * 256;
            int r = c >> 3, g = c & 7;
            short8 av = *(const short8*)(ATT + (size_t)(n0 + r) * 512 + j0 + g * 8);
            *(short8*)(As + r * 64 + ((g * 8) ^ ((r & 7) << 3))) = av;
            short8 bv = *(const short8*)(Wo + (size_t)(m0 + r) * 512 + j0 + g * 8);
            *(short8*)(Bs + r * 64 + ((g * 8) ^ ((r & 7) << 3))) = bv;
        }
        __syncthreads();
        const int arow = w * 16 + l15;
        short8 a0 = *(const short8*)(As + arow * 64 + ((lg * 8) ^ ((arow & 7) << 3)));
        short8 a1 = *(const short8*)(As + arow * 64 + ((32 + lg * 8) ^ ((arow & 7) << 3)));
        #pragma unroll
        for (int dc = 0; dc < 4; ++dc) {
            const int brow = dc * 16 + l15;
            short8 b0 = *(const short8*)(Bs + brow * 64 + ((lg * 8) ^ ((brow & 7) << 3)));
            acc[dc] = __builtin_amdgcn_mfma_f32_16x16x32_bf16(a0, b0, acc[dc], 0, 0, 0);
            short8 b1 = *(const short8*)(Bs + brow * 64 + ((32 + lg * 8) ^ ((brow & 7) << 3)));
            acc[dc] = __builtin_amdgcn_mfma_f32_16x16x32_bf16(a1, b1, acc[dc], 0, 0, 0);
        }
    }

    #pragma unroll
    for (int dc = 0; dc < 4; ++dc) {
        float bm = bias[m0 + dc * 16 + l15];
        #pragma unroll
        for (int reg = 0; reg < 4; ++reg) {
            int n = n0 + w * 16 + lg * 4 + reg;
            out[(size_t)n * D_MODEL + m0 + dc * 16 + l15] = acc[dc][reg] + bm;
        }
    }
}

extern "C" void kernel_launch(void* const* d_in, const int* in_sizes, int n_in,
                              void* d_out, int out_size, void* d_ws, size_t ws_size,
                              hipStream_t stream)
{
    const float* q      = (const float*)d_in[0];
    const float* k      = (const float*)d_in[1];
    const float* v      = (const float*)d_in[2];
    const float* coords = (const float*)d_in[3];
    const unsigned char* mask = (const unsigned char*)d_in[4];
    const float* q_proj = (const float*)d_in[5];
    const float* k_proj = (const float*)d_in[6];
    const float* v_proj = (const float*)d_in[7];
    const float* q_ln_w = (const float*)d_in[8];
    const float* q_ln_b = (const float*)d_in[9];
    const float* k_ln_w = (const float*)d_in[10];
    const float* k_ln_b = (const float*)d_in[11];
    const float* v_ln_w = (const float*)d_in[12];
    const float* v_ln_b = (const float*)d_in[13];
    const float* out_w  = (const float*)d_in[14];
    const float* out_b  = (const float*)d_in[15];
    float* out = (float*)d_out;

    // workspace layout (offsets in shorts)
    short* Xbf = (short*)d_ws;             // 3*2048*512
    short* Wt  = Xbf + 3145728;            // 3*512*512
    short* Wo  = Wt + 786432;              // 512*512
    short* Qbf = Wo + 262144;              // 8*2048*64
    short* Kf  = Qbf + 1048576;            // fragment-ordered
    short* Vf  = Kf + 1048576;             // fragment-ordered
    short* ATT = Vf + 1048576;             // [n][h*64+d] bf16
    float*  fr   = (float*)(ATT + 1048576);
    float4* ck4  = (float4*)fr;            // 8*2048 float4
    float*  mpen = fr + 65536;             // 2048
    unsigned* tflag = (unsigned*)(mpen + 2048);  // 32

    // overlays: Xbf/Wt are dead once proj_ln_mfma has run (stream-ordered)
    short* PO = Xbf;                       // 2*8*2048*64 bf16 = 4.2MB <= 6.3MB
    float* PM = (float*)Wt;                // 2*8*2048 f32
    float* PL = PM + 32768;                // 2*8*2048 f32  (512KB <= 1.5MB)

    convert_x_kernel<<<dim3(1536), dim3(256), 0, stream>>>(q, k, v, Xbf);
    prep_w_kernel<<<dim3(8, 8, 4), dim3(256), 0, stream>>>(q_proj, k_proj, v_proj, out_w, Wt, Wo);
    prep_rbf_kernel<<<dim3(8), dim3(256), 0, stream>>>(coords, mask, ck4, mpen, tflag);
    proj_ln_mfma_kernel<<<dim3(32, 8, 3), dim3(256), 0, stream>>>(
        Xbf, Wt, q_ln_w, q_ln_b, k_ln_w, k_ln_b, v_ln_w, v_ln_b, Qbf, Kf, Vf);
    attn_kernel<<<dim3(128, 8, 2), dim3(256), 0, stream>>>(
        Qbf, Kf, Vf, coords, ck4, mpen, tflag, PO, PM, PL);
    merge_kernel<<<dim3(512, 8), dim3(256), 0, stream>>>(PO, PM, PL, ATT);
    out_proj_kernel<<<dim3(32, 8), dim3(256), 0, stream>>>(ATT, Wo, out_b, out);
}

// Round 9
// 74.316 us; speedup vs baseline: 1.1301x; 1.0626x over previous
//
#include <hip/hip_runtime.h>
#include <math.h>

#define N_TOK 2048
#define D_MODEL 512
#define NHEAD 8
#define DK 64
#define LOG2E 1.44269504f
#define QSCALE 0.18033688f   // 0.125 * log2(e)

typedef __attribute__((ext_vector_type(8))) short short8;
typedef __attribute__((ext_vector_type(4))) short short4v;
typedef __attribute__((ext_vector_type(4))) float f32x4;

__device__ __forceinline__ short f2bf(float x) {
    unsigned u = __float_as_uint(x);
    u = (u + 0x7fffu + ((u >> 16) & 1u)) >> 16;   // round-to-nearest-even
    return (short)u;
}

__device__ __forceinline__ float bf2f(short s) {
    return __uint_as_float(((unsigned)(unsigned short)s) << 16);
}

__device__ __forceinline__ unsigned cvt_pk_bf16(float lo, float hi) {
    unsigned r;
    asm("v_cvt_pk_bf16_f32 %0, %1, %2" : "=v"(r) : "v"(lo), "v"(hi));
    return r;
}

__device__ __forceinline__ float head_c(int h) {
    // c_h = -log2e / (2*spread^2), spread = 1 + 5*(20^(h/7)-1)/19
    float tt = (float)h * (1.0f / 7.0f);
    float sp = 1.0f + 5.0f * (__builtin_exp2f(tt * 4.3219281f) - 1.0f) * (1.0f / 19.0f);
    return -LOG2E / (2.0f * sp * sp);
}

// ---------------- Prep A: x (q,k,v) f32 -> bf16 ----------------
__global__ __launch_bounds__(256) void convert_x_kernel(
    const float* __restrict__ q, const float* __restrict__ k,
    const float* __restrict__ v, short* __restrict__ Xbf)
{
    int i = blockIdx.x * 256 + threadIdx.x;
    int t = i >> 17;
    int rem = i & 131071;
    const float4* src = (const float4*)(t == 0 ? q : (t == 1 ? k : v));
    float4 a = src[rem * 2], b = src[rem * 2 + 1];
    short8 o;
    o[0] = f2bf(a.x); o[1] = f2bf(a.y); o[2] = f2bf(a.z); o[3] = f2bf(a.w);
    o[4] = f2bf(b.x); o[5] = f2bf(b.y); o[6] = f2bf(b.z); o[7] = f2bf(b.w);
    *(short8*)(Xbf + (size_t)i * 8) = o;
}

// ---------------- Prep B: weights -> bf16 (proj transposed) ----------------
// z<3: Wt[z][h*64+c][d] = proj_z[h][d][c].
// z==3: Wo[m][h*64+k] = out_w[m][k*8+h]  (K-dim permuted to match ATT layout).
__global__ __launch_bounds__(256) void prep_w_kernel(
    const float* __restrict__ qp, const float* __restrict__ kp,
    const float* __restrict__ vp, const float* __restrict__ ow,
    short* __restrict__ Wt, short* __restrict__ Wo)
{
    const int z = blockIdx.z, t = threadIdx.x;
    if (z == 3) {
        int m0 = blockIdx.x * 64, j0 = blockIdx.y * 64;
        int hh = j0 >> 6;
        for (int i = t; i < 4096; i += 256) {
            int r = i >> 6, kk = i & 63;
            Wo[(size_t)(m0 + r) * 512 + j0 + kk] =
                f2bf(ow[(size_t)(m0 + r) * 512 + kk * 8 + hh]);
        }
        return;
    }
    const float* src = z == 0 ? qp : (z == 1 ? kp : vp);
    __shared__ float tile[64][65];
    const int h = blockIdx.x;
    const int d0 = blockIdx.y * 64;
    for (int i = t; i < 4096; i += 256) {
        int r = i >> 6, c = i & 63;
        tile[r][c] = src[((size_t)h * 512 + d0 + r) * 64 + c];
    }
    __syncthreads();
    short* W = Wt + (size_t)z * 512 * 512;
    for (int i = t; i < 4096; i += 256) {
        int cr = i >> 6, dc_ = i & 63;
        W[(size_t)(h * 64 + cr) * 512 + d0 + dc_] = f2bf(tile[dc_][cr]);
    }
}

// ---------------- Prep C: RBF tables ----------------
// ck4[h][j] = {-2c_h*kx, -2c_h*ky, -2c_h*kz, c_h*|k|^2}; mpen[j]; tflag[j/64]
__global__ __launch_bounds__(256) void prep_rbf_kernel(
    const float* __restrict__ coords, const unsigned char* __restrict__ mask,
    float4* __restrict__ ck4, float* __restrict__ mpen, unsigned* __restrict__ tflag)
{
    int j = blockIdx.x * 256 + threadIdx.x;
    float x = coords[j * 3 + 0], y = coords[j * 3 + 1], z = coords[j * 3 + 2];
    unsigned char mk = mask[j];
    mpen[j] = mk ? -1e9f : 0.f;
    unsigned long long b = __ballot(mk != 0);
    if ((threadIdx.x & 63) == 0) tflag[j >> 6] = (b != 0ull) ? 1u : 0u;
    float n2 = x * x + y * y + z * z;
    #pragma unroll
    for (int h = 0; h < NHEAD; ++h) {
        float c = head_c(h);
        float4 o; o.x = -2.f * c * x; o.y = -2.f * c * y; o.z = -2.f * c * z; o.w = c * n2;
        ck4[(size_t)h * N_TOK + j] = o;
    }
}

// ---------------- Stage 1: projection + LayerNorm via bf16 MFMA ------------
// z=0: Q row-major [h][n][dk], pre-scaled by 0.125*log2e.
// z=1: K in MFMA-fragment tile order. z=2: V in fragment tile order (B=V^T A-op).
__global__ __launch_bounds__(256) void proj_ln_mfma_kernel(
    const short* __restrict__ Xbf, const short* __restrict__ Wt,
    const float* __restrict__ qlw, const float* __restrict__ qlb,
    const float* __restrict__ klw, const float* __restrict__ klb,
    const float* __restrict__ vlw, const float* __restrict__ vlb,
    short* __restrict__ Qbf, short* __restrict__ Kf, short* __restrict__ Vf)
{
    __shared__ short Xs[64 * 64];
    __shared__ short Ws[64 * 64];
    const int z = blockIdx.z, h = blockIdx.y;
    const int n0 = blockIdx.x * 64;
    const int tid = threadIdx.x, w = tid >> 6, l = tid & 63;
    const int l15 = l & 15, lg = l >> 4;

    const short* X = Xbf + (size_t)z * N_TOK * D_MODEL;
    const short* Wz = Wt + ((size_t)z * 512 + h * 64) * 512;

    const f32x4 zero4 = {0.f, 0.f, 0.f, 0.f};
    f32x4 acc[4];
    #pragma unroll
    for (int dc = 0; dc < 4; ++dc) acc[dc] = zero4;

    for (int kb = 0; kb < 8; ++kb) {
        const int d0 = kb * 64;
        __syncthreads();
        #pragma unroll
        for (int i = 0; i < 2; ++i) {
            int c = tid + i * 256;
            int r = c >> 3, g = c & 7;
            short8 xv = *(const short8*)(X + (size_t)(n0 + r) * 512 + d0 + g * 8);
            *(short8*)(Xs + r * 64 + ((g * 8) ^ ((r & 7) << 3))) = xv;
            short8 wv = *(const short8*)(Wz + (size_t)r * 512 + d0 + g * 8);
            *(short8*)(Ws + r * 64 + ((g * 8) ^ ((r & 7) << 3))) = wv;
        }
        __syncthreads();
        const int arow = w * 16 + l15;
        short8 a0 = *(const short8*)(Xs + arow * 64 + ((lg * 8) ^ ((arow & 7) << 3)));
        short8 a1 = *(const short8*)(Xs + arow * 64 + ((32 + lg * 8) ^ ((arow & 7) << 3)));
        #pragma unroll
        for (int dc = 0; dc < 4; ++dc) {
            const int brow = dc * 16 + l15;
            short8 b0 = *(const short8*)(Ws + brow * 64 + ((lg * 8) ^ ((brow & 7) << 3)));
            acc[dc] = __builtin_amdgcn_mfma_f32_16x16x32_bf16(a0, b0, acc[dc], 0, 0, 0);
            short8 b1 = *(const short8*)(Ws + brow * 64 + ((32 + lg * 8) ^ ((brow & 7) << 3)));
            acc[dc] = __builtin_amdgcn_mfma_f32_16x16x32_bf16(a1, b1, acc[dc], 0, 0, 0);
        }
    }

    const float* lw  = z == 0 ? qlw : (z == 1 ? klw : vlw);
    const float* lbp = z == 0 ? qlb : (z == 1 ? klb : vlb);
    float wv_[4], bv_[4];
    #pragma unroll
    for (int dc = 0; dc < 4; ++dc) {
        wv_[dc] = lw[dc * 16 + l15];
        bv_[dc] = lbp[dc * 16 + l15];
    }
    float mu[4], rs[4];
    #pragma unroll
    for (int reg = 0; reg < 4; ++reg) {
        float s = acc[0][reg] + acc[1][reg] + acc[2][reg] + acc[3][reg];
        #pragma unroll
        for (int off = 1; off < 16; off <<= 1) s += __shfl_xor(s, off);
        float m = s * (1.0f / 64.0f);
        float ss = 0.f;
        #pragma unroll
        for (int dc = 0; dc < 4; ++dc) { float d = acc[dc][reg] - m; ss += d * d; }
        #pragma unroll
        for (int off = 1; off < 16; off <<= 1) ss += __shfl_xor(ss, off);
        mu[reg] = m;
        rs[reg] = rsqrtf(ss * (1.0f / 64.0f) + 1e-5f);
    }

    const int tile = n0 >> 6;
    if (z == 0) {
        #pragma unroll
        for (int dc = 0; dc < 4; ++dc)
            #pragma unroll
            for (int reg = 0; reg < 4; ++reg) {
                int n = n0 + w * 16 + lg * 4 + reg;
                float val = ((acc[dc][reg] - mu[reg]) * rs[reg] * wv_[dc] + bv_[dc]) * QSCALE;
                Qbf[((size_t)h * N_TOK + n) * DK + dc * 16 + l15] = f2bf(val);
            }
    } else if (z == 1) {
        // fragment order: Kf[h] + tile*4096 + (nc*2+hf)*512 + (l15c+16*lgc)*8 + e
        short* Kh = Kf + (size_t)h * N_TOK * DK;
        #pragma unroll
        for (int dc = 0; dc < 4; ++dc) {
            int hf  = dc >> 1;
            int lgc = ((dc & 1) << 1) | (l15 >> 3);
            int e   = l15 & 7;
            size_t base = (size_t)tile * 4096 + (w * 2 + hf) * 512 + 16 * 8 * lgc + e;
            #pragma unroll
            for (int reg = 0; reg < 4; ++reg) {
                float val = (acc[dc][reg] - mu[reg]) * rs[reg] * wv_[dc] + bv_[dc];
                Kh[base + (lg * 4 + reg) * 8] = f2bf(val);
            }
        }
    } else {
        // fragment order: Vf[h] + tile*4096 + (dcc*2+hf)*512 + (l15+16*lgv)*8 + e
        short* Vh = Vf + (size_t)h * N_TOK * DK;
        int hfv = w >> 1;
        int lgv = ((w & 1) << 1) | (lg >> 1);
        int eb  = (lg & 1) * 4;
        #pragma unroll
        for (int dc = 0; dc < 4; ++dc) {
            short4v p;
            #pragma unroll
            for (int reg = 0; reg < 4; ++reg)
                p[reg] = f2bf((acc[dc][reg] - mu[reg]) * rs[reg] * wv_[dc] + bv_[dc]);
            size_t addr = (size_t)tile * 4096 + (dc * 2 + hfv) * 512 + (l15 + 16 * lgv) * 8 + eb;
            *(short4v*)(Vh + addr) = p;
        }
    }
}

// ---------------- Stage 2: split-K flash attention (bf16 MFMA) -------------
// 1-D grid 2048 with head<->XCD affinity: h = bid & 7 puts every block of
// head h on XCD h (round-robin dispatch) -> per-XCD L2 working set ~1.6MB
// (one head's K/V/Q/ck4), fully L2-resident. Block covers keys
// [z*1024,(z+1)*1024); wave w covers 256 keys in 4 steps of 64.
// m=0 softmax: LN'd q,k bound |s|*log2e <= ~10.4 -> P <= 1365, l <= 3e6,
// f32-safe without running max; merges are plain sums.
__global__ __launch_bounds__(256) void attn_kernel(
    const short* __restrict__ Qbf, const short* __restrict__ Kf,
    const short* __restrict__ Vf, const float* __restrict__ coords,
    const float4* __restrict__ ck4, const float* __restrict__ mpen,
    const unsigned* __restrict__ tflag,
    short* __restrict__ PO, float* __restrict__ PL)
{
    __shared__ short Pls[4][1024];       // per-wave P [16 q][64 k], swizzled
    __shared__ float bufO[2][64][17];
    __shared__ float bufL[2][64];

    const int tid = threadIdx.x;
    const int w = tid >> 6, l = tid & 63;
    const int l15 = l & 15, lg = l >> 4;
    const int bid = blockIdx.x;
    const int h  = bid & 7;              // head == XCD
    const int nt = (bid >> 3) & 127;
    const int z  = bid >> 10;
    const int n0 = nt * 16;

    char* Pb = (char*)&Pls[w][0];
    const int psw = (l15 & 7) << 4;      // byte-xor swizzle within 128B row

    // Q B-fragments (row q = n0+l15, d-halves)
    const short* Qrow = Qbf + ((size_t)h * N_TOK + n0 + l15) * DK + lg * 8;
    const short8 qf0 = *(const short8*)(Qrow);
    const short8 qf1 = *(const short8*)(Qrow + 32);

    const float ch = head_c(h);
    const float qx = coords[(n0 + l15) * 3 + 0];
    const float qy = coords[(n0 + l15) * 3 + 1];
    const float qz = coords[(n0 + l15) * 3 + 2];
    const float cq2 = ch * (qx * qx + qy * qy + qz * qz);
    const float4* ckh = ck4 + (size_t)h * N_TOK;

    const f32x4 zero4 = {0.f, 0.f, 0.f, 0.f};
    float l_ = 0.f;
    f32x4 oacc[4];
    #pragma unroll
    for (int i = 0; i < 4; ++i) oacc[i] = zero4;

    const short* Kfh = Kf + (size_t)h * N_TOK * DK;
    const short* Vfh = Vf + (size_t)h * N_TOK * DK;

    for (int t = 0; t < 4; ++t) {
        const int kt = (z * 4 + w) * 4 + t;  // global 64-key tile
        const int kbase = kt * 64;
        const short* kp = Kfh + (size_t)kt * 4096 + l * 8;
        const short* vp = Vfh + (size_t)kt * 4096 + l * 8;

        // ---- QK^T (swapped): S^T[k][q], lane: q=l15, k = nc*16+lg*4+reg ----
        f32x4 sacc[4];
        #pragma unroll
        for (int nc = 0; nc < 4; ++nc) {
            short8 k0 = *(const short8*)(kp + nc * 1024);
            short8 k1 = *(const short8*)(kp + nc * 1024 + 512);
            sacc[nc] = __builtin_amdgcn_mfma_f32_16x16x32_bf16(k0, qf0, zero4, 0, 0, 0);
            sacc[nc] = __builtin_amdgcn_mfma_f32_16x16x32_bf16(k1, qf1, sacc[nc], 0, 0, 0);
        }

        // ---- RBF modulation (log2 domain; Q pre-scaled by 0.125*log2e) ----
        #pragma unroll
        for (int nc = 0; nc < 4; ++nc) {
            #pragma unroll
            for (int reg = 0; reg < 4; ++reg) {
                float4 c4 = ckh[kbase + nc * 16 + lg * 4 + reg];
                float arg = fmaf(c4.x, qx, fmaf(c4.y, qy, fmaf(c4.z, qz, c4.w))) + cq2;
                float rb = __builtin_exp2f(arg);
                rb = fminf(fmaxf(rb, 0.1f), 0.9f);
                sacc[nc][reg] *= rb;
            }
        }
        if (tflag[kt]) {
            #pragma unroll
            for (int nc = 0; nc < 4; ++nc)
                #pragma unroll
                for (int reg = 0; reg < 4; ++reg)
                    sacc[nc][reg] += mpen[kbase + nc * 16 + lg * 4 + reg];
        }

        // ---- P = exp2(s) (m=0), sum, pack -> LDS (b64 per nc) ----
        float ps = 0.f;
        #pragma unroll
        for (int nc = 0; nc < 4; ++nc) {
            float p0 = __builtin_exp2f(sacc[nc][0]);
            float p1 = __builtin_exp2f(sacc[nc][1]);
            float p2 = __builtin_exp2f(sacc[nc][2]);
            float p3 = __builtin_exp2f(sacc[nc][3]);
            ps += (p0 + p1) + (p2 + p3);
            uint2 u;
            u.x = cvt_pk_bf16(p0, p1);
            u.y = cvt_pk_bf16(p2, p3);
            *(uint2*)(Pb + ((l15 * 128 + nc * 32 + lg * 8) ^ psw)) = u;
        }
        ps += __shfl_xor(ps, 16);
        ps += __shfl_xor(ps, 32);
        l_ += ps;

        // ---- PV (swapped): O^T += V^T * P^T; lane: q=l15, d=dcc*16+lg*4+reg
        short8 pf0 = *(const short8*)(Pb + ((l15 * 128 + lg * 16) ^ psw));
        short8 pf1 = *(const short8*)(Pb + ((l15 * 128 + 64 + lg * 16) ^ psw));
        #pragma unroll
        for (int dcc = 0; dcc < 4; ++dcc) {
            short8 v0 = *(const short8*)(vp + dcc * 1024);
            short8 v1 = *(const short8*)(vp + dcc * 1024 + 512);
            oacc[dcc] = __builtin_amdgcn_mfma_f32_16x16x32_bf16(v0, pf0, oacc[dcc], 0, 0, 0);
            oacc[dcc] = __builtin_amdgcn_mfma_f32_16x16x32_bf16(v1, pf1, oacc[dcc], 0, 0, 0);
        }
    }

    // ---- cross-wave tree merge (m=0: plain sums, lane-aligned) ----
    if (w >= 2) {
        int slot = w - 2;
        bufL[slot][l] = l_;
        #pragma unroll
        for (int dc = 0; dc < 4; ++dc)
            #pragma unroll
            for (int reg = 0; reg < 4; ++reg)
                bufO[slot][l][dc * 4 + reg] = oacc[dc][reg];
    }
    __syncthreads();
    if (w < 2) {
        l_ += bufL[w][l];
        #pragma unroll
        for (int dc = 0; dc < 4; ++dc)
            #pragma unroll
            for (int reg = 0; reg < 4; ++reg)
                oacc[dc][reg] += bufO[w][l][dc * 4 + reg];
    }
    __syncthreads();
    if (w == 1) {
        bufL[0][l] = l_;
        #pragma unroll
        for (int dc = 0; dc < 4; ++dc)
            #pragma unroll
            for (int reg = 0; reg < 4; ++reg)
                bufO[0][l][dc * 4 + reg] = oacc[dc][reg];
    }
    __syncthreads();
    if (w == 0) {
        float lf = l_ + bufL[0][l];
        size_t p = ((size_t)z * NHEAD + h) * N_TOK + n0 + l15;
        if (lg == 0) PL[p] = lf;
        #pragma unroll
        for (int dcc = 0; dcc < 4; ++dcc) {
            short4v o4;
            #pragma unroll
            for (int reg = 0; reg < 4; ++reg)
                o4[reg] = f2bf(oacc[dcc][reg] + bufO[0][l][dcc * 4 + reg]);
            *(short4v*)(PO + p * 64 + dcc * 16 + lg * 4) = o4;
        }
    }
}

// ---------------- Stage 2b: merge the 2 KV-split partials ------------------
// grid (N/4, H), block 256 = 4 waves; wave u owns q = bx*4+u, lane = d.
// ATT layout: [n][h*64+d] (Wo K-dim permuted to match). m=0: plain sums.
__global__ __launch_bounds__(256) void merge_kernel(
    const short* __restrict__ PO, const float* __restrict__ PL,
    short* __restrict__ ATT)
{
    const int t = threadIdx.x;
    const int u = t >> 6, d = t & 63;
    const int q = blockIdx.x * 4 + u;
    const int h = blockIdx.y;
    const size_t p0 = (size_t)h * N_TOK + q;
    const size_t p1 = (size_t)(NHEAD + h) * N_TOK + q;
    float rl = 1.0f / (PL[p0] + PL[p1]);
    float o0 = bf2f(PO[p0 * 64 + d]), o1 = bf2f(PO[p1 * 64 + d]);
    ATT[(size_t)q * D_MODEL + h * 64 + d] = f2bf((o0 + o1) * rl);
}

// ---------------- Stage 3: output projection via bf16 MFMA ----------------
__global__ __launch_bounds__(256) void out_proj_kernel(
    const short* __restrict__ ATT, const short* __restrict__ Wo,
    const float* __restrict__ bias, float* __restrict__ out)
{
    __shared__ short As[64 * 64];
    __shared__ short Bs[64 * 64];
    const int n0 = blockIdx.x * 64, m0 = blockIdx.y * 64;
    const int tid = threadIdx.x, w = tid >> 6, l = tid & 63;
    const int l15 = l & 15, lg = l >> 4;

    const f32x4 zero4 = {0.f, 0.f, 0.f, 0.f};
    f32x4 acc[4];
    #pragma unroll
    for (int dc = 0; dc < 4; ++dc) acc[dc] = zero4;

    for (int kb = 0; kb < 8; ++kb) {
        const int j0 = kb * 64;
        __syncthreads();
        #pragma unroll
        for (int i = 0; i < 2; ++i) {
            int c = tid + i * 256;
            int r = c >> 3, g = c & 7;
            short8 av = *(const short8*)(ATT + (size_t)(n0 + r) * 512 + j0 + g * 8);
            *(short8*)(As + r * 64 + ((g * 8) ^ ((r & 7) << 3))) = av;
            short8 bv = *(const short8*)(Wo + (size_t)(m0 + r) * 512 + j0 + g * 8);
            *(short8*)(Bs + r * 64 + ((g * 8) ^ ((r & 7) << 3))) = bv;
        }
        __syncthreads();
        const int arow = w * 16 + l15;
        short8 a0 = *(const short8*)(As + arow * 64 + ((lg * 8) ^ ((arow & 7) << 3)));
        short8 a1 = *(const short8*)(As + arow * 64 + ((32 + lg * 8) ^ ((arow & 7) << 3)));
        #pragma unroll
        for (int dc = 0; dc < 4; ++dc) {
            const int brow = dc * 16 + l15;
            short8 b0 = *(const short8*)(Bs + brow * 64 + ((lg * 8) ^ ((brow & 7) << 3)));
            acc[dc] = __builtin_amdgcn_mfma_f32_16x16x32_bf16(a0, b0, acc[dc], 0, 0, 0);
            short8 b1 = *(const short8*)(Bs + brow * 64 + ((32 + lg * 8) ^ ((brow & 7) << 3)));
            acc[dc] = __builtin_amdgcn_mfma_f32_16x16x32_bf16(a1, b1, acc[dc], 0, 0, 0);
        }
    }

    #pragma unroll
    for (int dc = 0; dc < 4; ++dc) {
        float bm = bias[m0 + dc * 16 + l15];
        #pragma unroll
        for (int reg = 0; reg < 4; ++reg) {
            int n = n0 + w * 16 + lg * 4 + reg;
            out[(size_t)n * D_MODEL + m0 + dc * 16 + l15] = acc[dc][reg] + bm;
        }
    }
}

extern "C" void kernel_launch(void* const* d_in, const int* in_sizes, int n_in,
                              void* d_out, int out_size, void* d_ws, size_t ws_size,
                              hipStream_t stream)
{
    const float* q      = (const float*)d_in[0];
    const float* k      = (const float*)d_in[1];
    const float* v      = (const float*)d_in[2];
    const float* coords = (const float*)d_in[3];
    const unsigned char* mask = (const unsigned char*)d_in[4];
    const float* q_proj = (const float*)d_in[5];
    const float* k_proj = (const float*)d_in[6];
    const float* v_proj = (const float*)d_in[7];
    const float* q_ln_w = (const float*)d_in[8];
    const float* q_ln_b = (const float*)d_in[9];
    const float* k_ln_w = (const float*)d_in[10];
    const float* k_ln_b = (const float*)d_in[11];
    const float* v_ln_w = (const float*)d_in[12];
    const float* v_ln_b = (const float*)d_in[13];
    const float* out_w  = (const float*)d_in[14];
    const float* out_b  = (const float*)d_in[15];
    float* out = (float*)d_out;

    // workspace layout (offsets in shorts)
    short* Xbf = (short*)d_ws;             // 3*2048*512
    short* Wt  = Xbf + 3145728;            // 3*512*512
    short* Wo  = Wt + 786432;              // 512*512
    short* Qbf = Wo + 262144;              // 8*2048*64
    short* Kf  = Qbf + 1048576;            // fragment-ordered
    short* Vf  = Kf + 1048576;             // fragment-ordered
    short* ATT = Vf + 1048576;             // [n][h*64+d] bf16
    float*  fr   = (float*)(ATT + 1048576);
    float4* ck4  = (float4*)fr;            // 8*2048 float4
    float*  mpen = fr + 65536;             // 2048
    unsigned* tflag = (unsigned*)(mpen + 2048);  // 32

    // overlays: Xbf/Wt are dead once proj_ln_mfma has run (stream-ordered)
    short* PO = Xbf;                       // 2*8*2048*64 bf16 = 4.2MB <= 6.3MB
    float* PL = (float*)Wt;                // 2*8*2048 f32

    convert_x_kernel<<<dim3(1536), dim3(256), 0, stream>>>(q, k, v, Xbf);
    prep_w_kernel<<<dim3(8, 8, 4), dim3(256), 0, stream>>>(q_proj, k_proj, v_proj, out_w, Wt, Wo);
    prep_rbf_kernel<<<dim3(8), dim3(256), 0, stream>>>(coords, mask, ck4, mpen, tflag);
    proj_ln_mfma_kernel<<<dim3(32, 8, 3), dim3(256), 0, stream>>>(
        Xbf, Wt, q_ln_w, q_ln_b, k_ln_w, k_ln_b, v_ln_w, v_ln_b, Qbf, Kf, Vf);
    attn_kernel<<<dim3(2048), dim3(256), 0, stream>>>(
        Qbf, Kf, Vf, coords, ck4, mpen, tflag, PO, PL);
    merge_kernel<<<dim3(512, 8), dim3(256), 0, stream>>>(PO, PL, ATT);
    out_proj_kernel<<<dim3(32, 8), dim3(256), 0, stream>>>(ATT, Wo, out_b, out);
}